// Round 8
// baseline (1038.456 us; speedup 1.0000x reference)
//
#include <hip/hip_runtime.h>
#include <math.h>

typedef _Float16 f16;
typedef f16 f16x8 __attribute__((ext_vector_type(8)));
typedef float f32x4 __attribute__((ext_vector_type(4)));

#define B_ 8
#define D_ 256
#define T_ 8192
#define NQ 8
#define KB 1024
#define TT 64
#define NTHR 512

#define OUT_CODES (B_ * D_ * T_)      // 16777216
#define OUT_BW (OUT_CODES + NQ * B_ * T_)
#define OUT_LOSS (OUT_BW + 1)

// rs: 64 rows x 512 halves (h1 granules 0..31, true-lo granules 32..63),
// granule (8 halves) swizzled: stored at g ^ (t & 7). No pad.
#define R_BYTES 65536
#define RED_OFF R_BYTES               // redv[512] f32 (8 waves x 64 rows)
#define REDI_OFF (RED_OFF + 2048)     // redi[512] i32
#define WSUM_OFF (REDI_OFF + 2048)    // wsum[8]
#define LDS_TOTAL (WSUM_OFF + 32)     // 69664 -> 2 blocks/CU

// workspace layout
#define WS_HI (8192 * 4)              // csq first (32KB)
#define CBW_HALVES (NQ * 8 * KB * 32) // 2,097,152 halves per array
#define WS_LO (WS_HI + CBW_HALVES * 2)

#define MFMA16(a, b, c) __builtin_amdgcn_mfma_f32_16x16x32_f16(a, b, c, 0, 0, 0)

// ---------------- init: codebook row norms (fp32) + scalar outputs ----------------
__global__ void init_cbsq_kernel(const float* __restrict__ cb, const int* __restrict__ sr,
                                 float* __restrict__ csq, float* __restrict__ out) {
    int gid = blockIdx.x * blockDim.x + threadIdx.x;
    int row = gid >> 6;
    int lane = gid & 63;
    float4 v = ((const float4*)(cb + (size_t)row * D_))[lane];
    float s = fmaf(v.x, v.x, fmaf(v.y, v.y, fmaf(v.z, v.z, v.w * v.w)));
#pragma unroll
    for (int off = 32; off; off >>= 1) s += __shfl_down(s, off);
    if (lane == 0) csq[row] = s;
    if (gid == 0) {
        out[OUT_BW] = (float)(*sr) * (80.0f / 1000.0f);
        out[OUT_LOSS] = 0.0f;
    }
}

// ---------------- init: split codebook into f16 hi + TRUE lo, [q][dc8][code][32] ----------------
__global__ void init_split_kernel(const float* __restrict__ cb, f16* __restrict__ whi,
                                  f16* __restrict__ wlo) {
    int gid = blockIdx.x * 256 + threadIdx.x;   // (q*8+dc)*1024 + k
    int qdc = gid >> 10, k = gid & 1023;
    int q = qdc >> 3, dc = qdc & 7;
    const float* src = cb + ((size_t)(q * 1024 + k)) * 256 + dc * 32;
    size_t wo = (size_t)gid * 32;
#pragma unroll
    for (int jj = 0; jj < 4; ++jj) {
        float4 a = ((const float4*)src)[jj * 2];
        float4 c = ((const float4*)src)[jj * 2 + 1];
        float vals[8] = {a.x, a.y, a.z, a.w, c.x, c.y, c.z, c.w};
        f16x8 hv, lv;
#pragma unroll
        for (int i = 0; i < 8; ++i) {
            f16 h = (f16)vals[i];
            hv[i] = h;
            lv[i] = (f16)(vals[i] - (float)h);    // true lo (f16 subnormals cover it)
        }
        *(f16x8*)&whi[wo + jj * 8] = hv;
        *(f16x8*)&wlo[wo + jj * 8] = lv;
    }
}

// ---------------- main RVQ kernel: 3-product split-f16 MFMA GEMM ----------------
// 8 waves; EACH wave covers all 64 rows (mt=4) x 2 code-cols (nt=2); 4 sweeps of
// 256 codes -> B read EXACTLY ONCE per block per q.
// R8: (1) next-sweep / q-start B-prefetch issued while regs are dead (hides the
// sweep-boundary L2 latency the STEP fences otherwise expose); (2) DPP butterfly
// (quad_perm xor1/xor2 + row_ror:4/8 over the 16-lane row = complete min-network,
// bit-identical result, no ds_bpermute LDS round-trips); (3) cq hoisted to sweep
// top; (4) dc-loop fully unrolled (liveness capped by alternating B-sets + fences).
// Ledger unchanged: acc 32 + bval 16 + bidxp 8 + 2 B-sets 32 + A 16 + addr ~14
// = ~118 <= 128 (launch_bounds 512,4).
extern "C" __global__ __launch_bounds__(NTHR, 4)
void rvq_kernel(const float* __restrict__ x, const float* __restrict__ cb,
                const float* __restrict__ csq, const f16* __restrict__ whi,
                const f16* __restrict__ wlo, float* __restrict__ out) {
    extern __shared__ char smem[];
    f16* rs = (f16*)smem;                          // [64][512] halves, granule-swizzled
    float* redv = (float*)(smem + RED_OFF);
    int* redi = (int*)(smem + REDI_OFF);
    float* wsum = (float*)(smem + WSUM_OFF);

    const int tid = threadIdx.x;
    const int w = tid >> 6;
    const int l = tid & 63;
    const int l15 = l & 15;
    const int q4 = l >> 4;

    const int b = blockIdx.x >> 7;
    const int t0 = (blockIdx.x & 127) * TT;
    const float* xb = x + (size_t)b * D_ * T_;

    // residual init: rs[t][d] split of x[b][d][t0+t] (coalesced over t); swizzled store
    for (int d = tid >> 6; d < D_; d += 8) {
        float v = xb[(size_t)d * T_ + t0 + l];
        f16 h = (f16)v;
        const int sw = l & 7;
        rs[l * 512 + (((d >> 3) ^ sw) << 3) + (d & 7)] = h;
        rs[l * 512 + ((((d >> 3) + 32) ^ sw) << 3) + (d & 7)] = (f16)(v - (float)h);
    }

    float ssq = 0.0f;

    // A row-base: invariant across q/sweeps/dc (row = mt*16 + l15)
    const f16* a_base = rs + l15 * 512;
    const int swA = l15 & 7;                       // == row&7 for all A rows of this lane
    const int vb_s0 = ((w * 32 + l15) << 6) + q4 * 16;   // sweep-0 byte base

    for (int q = 0; q < NQ; ++q) {
        const float* cbq = cb + (size_t)q * KB * D_;
        const char* wq = (const char*)(whi + (size_t)q * 8 * KB * 32);
        const char* lq = (const char*)(wlo + (size_t)q * 8 * KB * 32);

        f16x8 sa0h, sa0l, sa1h, sa1l;              // B set A
        f16x8 sb0h, sb0l, sb1h, sb1l;              // B set B

#define LOADSET(p0h, p0l, p1h, p1l, dcv, vbv) { \
            const char* wd_ = wq + (dcv) * 65536; \
            const char* ld_ = lq + (dcv) * 65536; \
            p0h = *(const f16x8*)(wd_ + (vbv)); \
            p0l = *(const f16x8*)(ld_ + (vbv)); \
            p1h = *(const f16x8*)(wd_ + (vbv) + 1024); \
            p1l = *(const f16x8*)(ld_ + (vbv) + 1024); }

        // q-start B-prefetch ABOVE the barrier (B depends only on q, not rs)
        int vb = vb_s0;
        LOADSET(sa0h, sa0l, sa1h, sa1l, 0, vb)
        LOADSET(sb0h, sb0l, sb1h, sb1l, 1, vb)

        __syncthreads();   // rs ready (init or prev-q update); redv/redi free for this q

        // cross-sweep running best (slot e = mt*4+rg row ownership; codes ascend
        // across sweeps and nt -> strict < keeps first min). bidx packed 2x16b.
        float bval[16];
        unsigned bidxp[8];
#pragma unroll
        for (int e = 0; e < 16; ++e) bval[e] = INFINITY;
#pragma unroll
        for (int p = 0; p < 8; ++p) bidxp[p] = 0;

#define STEP(dcv, c0h, c0l, c1h, c1l) { \
            const int ga_ = (dcv) * 4 + q4; \
            const int o1_ = (ga_ ^ swA) << 3; \
            const int o2_ = ((ga_ + 32) ^ swA) << 3; \
            f16x8 afa1 = *(const f16x8*)&a_base[o1_]; \
            f16x8 afa2 = *(const f16x8*)&a_base[o2_]; \
            f16x8 afb1 = *(const f16x8*)&a_base[8192 + o1_]; \
            f16x8 afb2 = *(const f16x8*)&a_base[8192 + o2_]; \
            __builtin_amdgcn_s_setprio(1); \
            ah[0][0] = MFMA16(afa1, c0h, ah[0][0]); \
            ah[0][0] = MFMA16(afa2, c0h, ah[0][0]); \
            ah[0][0] = MFMA16(afa1, c0l, ah[0][0]); \
            ah[0][1] = MFMA16(afa1, c1h, ah[0][1]); \
            ah[0][1] = MFMA16(afa2, c1h, ah[0][1]); \
            ah[0][1] = MFMA16(afa1, c1l, ah[0][1]); \
            __builtin_amdgcn_sched_barrier(0); \
            afa1 = *(const f16x8*)&a_base[16384 + o1_]; \
            afa2 = *(const f16x8*)&a_base[16384 + o2_]; \
            ah[1][0] = MFMA16(afb1, c0h, ah[1][0]); \
            ah[1][0] = MFMA16(afb2, c0h, ah[1][0]); \
            ah[1][0] = MFMA16(afb1, c0l, ah[1][0]); \
            ah[1][1] = MFMA16(afb1, c1h, ah[1][1]); \
            ah[1][1] = MFMA16(afb2, c1h, ah[1][1]); \
            ah[1][1] = MFMA16(afb1, c1l, ah[1][1]); \
            __builtin_amdgcn_sched_barrier(0); \
            afb1 = *(const f16x8*)&a_base[24576 + o1_]; \
            afb2 = *(const f16x8*)&a_base[24576 + o2_]; \
            ah[2][0] = MFMA16(afa1, c0h, ah[2][0]); \
            ah[2][0] = MFMA16(afa2, c0h, ah[2][0]); \
            ah[2][0] = MFMA16(afa1, c0l, ah[2][0]); \
            ah[2][1] = MFMA16(afa1, c1h, ah[2][1]); \
            ah[2][1] = MFMA16(afa2, c1h, ah[2][1]); \
            ah[2][1] = MFMA16(afa1, c1l, ah[2][1]); \
            __builtin_amdgcn_sched_barrier(0); \
            ah[3][0] = MFMA16(afb1, c0h, ah[3][0]); \
            ah[3][0] = MFMA16(afb2, c0h, ah[3][0]); \
            ah[3][0] = MFMA16(afb1, c0l, ah[3][0]); \
            ah[3][1] = MFMA16(afb1, c1h, ah[3][1]); \
            ah[3][1] = MFMA16(afb2, c1h, ah[3][1]); \
            ah[3][1] = MFMA16(afb1, c1l, ah[3][1]); \
            __builtin_amdgcn_s_setprio(0); \
            __builtin_amdgcn_sched_barrier(0); }

#pragma unroll 1
        for (int s = 0; s < 4; ++s) {              // 4 sweeps of 256 codes; 32/wave (nt=2)
            const int code0 = s * 256 + w * 32 + l15;
            const float cq0 = csq[q * KB + code0];       // hoisted: hides L2 latency
            const float cq1 = csq[q * KB + code0 + 16];

            f32x4 ah[4][2];                        // 32 acc VGPRs
#pragma unroll
            for (int mt = 0; mt < 4; ++mt)
#pragma unroll
                for (int nt = 0; nt < 2; ++nt) ah[mt][nt] = (f32x4)0.0f;

#pragma unroll
            for (int dc2 = 0; dc2 < 6; dc2 += 2) {
                STEP(dc2, sa0h, sa0l, sa1h, sa1l)
                LOADSET(sa0h, sa0l, sa1h, sa1l, dc2 + 2, vb)
                STEP(dc2 + 1, sb0h, sb0l, sb1h, sb1l)
                LOADSET(sb0h, sb0l, sb1h, sb1l, dc2 + 3, vb)
            }
            STEP(6, sa0h, sa0l, sa1h, sa1l)
            // next-sweep prefetch into the just-freed set A, before STEP7 + fold
            const int vbn = vb + 16384;
            if (s < 3) { LOADSET(sa0h, sa0l, sa1h, sa1l, 0, vbn) }
            STEP(7, sb0h, sb0l, sb1h, sb1l)
            if (s < 3) { LOADSET(sb0h, sb0l, sb1h, sb1l, 1, vbn) }
            vb = vbn;

            // fold sweep into cross-sweep per-lane best (codes ascending -> strict <);
            // B-prefetch above is in flight under this VALU work.
#pragma unroll
            for (int nt = 0; nt < 2; ++nt) {
                const int code = code0 + nt * 16;
                const float cq = nt ? cq1 : cq0;
#pragma unroll
                for (int mt = 0; mt < 4; ++mt)
#pragma unroll
                    for (int rg = 0; rg < 4; ++rg) {
                        const int e = mt * 4 + rg;
                        const float dist = fmaf(-2.0f, ah[mt][nt][rg], cq);
                        if (dist < bval[e]) {
                            bval[e] = dist;
                            const int sh = (e & 1) * 16;
                            bidxp[e >> 1] = (bidxp[e >> 1] & ~(0xFFFFu << sh)) |
                                            ((unsigned)code << sh);
                        }
                    }
            }
        }
#undef STEP
#undef LOADSET

        // once per q: DPP min-network across the 16 lanes (codes) sharing each row.
        // quad_perm xor1 (0xB1), xor2 (0x4E), row_ror:4 (0x124), row_ror:8 (0x128)
        // form a complete mixing network over each aligned 16-lane row; lexicographic
        // (dist, code) min is associative+commutative -> identical result to the
        // xor-butterfly, with zero LDS traffic.
#define BFLY(CTRL) { \
        _Pragma("unroll") \
        for (int p = 0; p < 8; ++p) { \
            const unsigned op = (unsigned)__builtin_amdgcn_mov_dpp((int)bidxp[p], CTRL, 0xF, 0xF, false); \
            _Pragma("unroll") \
            for (int h = 0; h < 2; ++h) { \
                const int e = p * 2 + h; \
                const float ov = __int_as_float(__builtin_amdgcn_mov_dpp(__float_as_int(bval[e]), CTRL, 0xF, 0xF, false)); \
                const int sh = h * 16; \
                const unsigned oc = (op >> sh) & 0xFFFFu; \
                const unsigned mc = (bidxp[p] >> sh) & 0xFFFFu; \
                if (ov < bval[e] || (ov == bval[e] && oc < mc)) { \
                    bval[e] = ov; \
                    bidxp[p] = (bidxp[p] & ~(0xFFFFu << sh)) | (oc << sh); \
                } } } }
        BFLY(0xB1)
        BFLY(0x4E)
        BFLY(0x124)
        BFLY(0x128)
#undef BFLY

        if (l15 == 0) {
#pragma unroll
            for (int mt = 0; mt < 4; ++mt)
#pragma unroll
                for (int rg = 0; rg < 4; ++rg) {
                    const int e = mt * 4 + rg;
                    const int t = mt * 16 + q4 * 4 + rg;   // C-layout row ownership
                    redv[w * 64 + t] = bval[e];
                    redi[w * 64 + t] = (int)((bidxp[e >> 1] >> ((e & 1) * 16)) & 0xFFFFu);
                }
        }
        __syncthreads();   // all waves' redv/redi final; all GEMM rs reads done
        // merged final-reduce + residual update: thread -> (row t, 32-dim chunk ch)
        {
            const int t = tid & 63, ch = tid >> 6;
            float bv = redv[t];
            int bi = redi[t];
#pragma unroll
            for (int w2 = 1; w2 < 8; ++w2) {
                const float v = redv[w2 * 64 + t];
                const int ii = redi[w2 * 64 + t];
                if (v < bv || (v == bv && ii < bi)) { bv = v; bi = ii; }
            }
            if (ch == 0) out[OUT_CODES + ((size_t)q * B_ + b) * T_ + t0 + t] = (float)bi;
            // residual update: fp32 = hi + lo, subtract cb row, re-split; ssq
            const float* crow = cbq + (size_t)bi * D_ + ch * 32;
            f16* rowp = rs + t * 512;
            const int sw = t & 7;
#pragma unroll
            for (int jj = 0; jj < 4; ++jj) {
                const int g = ch * 4 + jj;
                const int g1 = (g ^ sw) << 3;
                const int g2 = ((g + 32) ^ sw) << 3;
                f16x8 hv = *(const f16x8*)&rowp[g1];
                f16x8 lv = *(const f16x8*)&rowp[g2];
                const float4 c0 = ((const float4*)crow)[jj * 2];
                const float4 c1 = ((const float4*)crow)[jj * 2 + 1];
                const float cc[8] = {c0.x, c0.y, c0.z, c0.w, c1.x, c1.y, c1.z, c1.w};
                f16x8 nh, nl;
#pragma unroll
                for (int i = 0; i < 8; ++i) {
                    const float r = (float)hv[i] + (float)lv[i];
                    const float nv = r - cc[i];
                    ssq = fmaf(nv, nv, ssq);
                    const f16 h = (f16)nv;
                    nh[i] = h;
                    nl[i] = (f16)(nv - (float)h);
                }
                *(f16x8*)&rowp[g1] = nh;
                *(f16x8*)&rowp[g2] = nl;
            }
        }
        // next q's top __syncthreads orders rs writes before A-frag reads
    }
    __syncthreads();
    // quantized = x - r_final, [B][D][T], coalesced over t
    {
        float* outq = out + (size_t)b * D_ * T_;
        for (int d = tid >> 6; d < D_; d += 8) {
            const int sw = l & 7;
            const float h1 = (float)rs[l * 512 + (((d >> 3) ^ sw) << 3) + (d & 7)];
            const float h2 = (float)rs[l * 512 + ((((d >> 3) + 32) ^ sw) << 3) + (d & 7)];
            const size_t gi = (size_t)d * T_ + t0 + l;
            outq[gi] = xb[gi] - (h1 + h2);
        }
    }
    // commit loss: wave reduce -> block reduce -> one atomic
#pragma unroll
    for (int off = 32; off; off >>= 1) ssq += __shfl_down(ssq, off);
    if (l == 0) wsum[w] = ssq;
    __syncthreads();
    if (tid == 0) {
        float tot = 0.0f;
#pragma unroll
        for (int i = 0; i < 8; ++i) tot += wsum[i];
        const float scale = 0.25f / ((float)NQ * (float)B_ * (float)D_ * (float)T_);
        atomicAdd(out + OUT_LOSS, tot * scale);
    }
}

extern "C" void kernel_launch(void* const* d_in, const int* in_sizes, int n_in,
                              void* d_out, int out_size, void* d_ws, size_t ws_size,
                              hipStream_t stream) {
    const float* x = (const float*)d_in[0];
    const int* sr = (const int*)d_in[1];
    const float* cb = (const float*)d_in[2];
    float* out = (float*)d_out;
    float* csq = (float*)d_ws;
    f16* whi = (f16*)((char*)d_ws + WS_HI);
    f16* wlo = (f16*)((char*)d_ws + WS_LO);

    hipFuncSetAttribute((const void*)rvq_kernel, hipFuncAttributeMaxDynamicSharedMemorySize,
                        LDS_TOTAL);

    init_cbsq_kernel<<<2048, 256, 0, stream>>>(cb, sr, csq, out);
    init_split_kernel<<<256, 256, 0, stream>>>(cb, whi, wlo);
    rvq_kernel<<<B_ * (T_ / TT), NTHR, LDS_TOTAL, stream>>>(x, cb, csq, whi, wlo, out);
}

// Round 9
// 974.065 us; speedup vs baseline: 1.0661x; 1.0661x over previous
//
#include <hip/hip_runtime.h>
#include <math.h>

typedef _Float16 f16;
typedef f16 f16x8 __attribute__((ext_vector_type(8)));
typedef float f32x4 __attribute__((ext_vector_type(4)));

#define B_ 8
#define D_ 256
#define T_ 8192
#define NQ 8
#define KB 1024
#define TT 64
#define NTHR 512

#define OUT_CODES (B_ * D_ * T_)      // 16777216
#define OUT_BW (OUT_CODES + NQ * B_ * T_)
#define OUT_LOSS (OUT_BW + 1)

// rs: 64 rows x 512 halves (h1 granules 0..31, true-lo granules 32..63),
// granule (8 halves) swizzled: stored at g ^ (t & 7). No pad.
#define R_BYTES 65536
#define RED_OFF R_BYTES               // redv[512] f32 (8 waves x 64 rows)
#define REDI_OFF (RED_OFF + 2048)     // redi[512] i32
#define WSUM_OFF (REDI_OFF + 2048)    // wsum[8]
#define LDS_TOTAL (WSUM_OFF + 32)     // 69664 -> 2 blocks/CU

// workspace layout
#define WS_HI (8192 * 4)              // csq first (32KB)
#define CBW_HALVES (NQ * 8 * KB * 32) // 2,097,152 halves per array
#define WS_LO (WS_HI + CBW_HALVES * 2)

#define MFMA16(a, b, c) __builtin_amdgcn_mfma_f32_16x16x32_f16(a, b, c, 0, 0, 0)

// ---------------- init: codebook row norms (fp32) + scalar outputs ----------------
__global__ void init_cbsq_kernel(const float* __restrict__ cb, const int* __restrict__ sr,
                                 float* __restrict__ csq, float* __restrict__ out) {
    int gid = blockIdx.x * blockDim.x + threadIdx.x;
    int row = gid >> 6;
    int lane = gid & 63;
    float4 v = ((const float4*)(cb + (size_t)row * D_))[lane];
    float s = fmaf(v.x, v.x, fmaf(v.y, v.y, fmaf(v.z, v.z, v.w * v.w)));
#pragma unroll
    for (int off = 32; off; off >>= 1) s += __shfl_down(s, off);
    if (lane == 0) csq[row] = s;
    if (gid == 0) {
        out[OUT_BW] = (float)(*sr) * (80.0f / 1000.0f);
        out[OUT_LOSS] = 0.0f;
    }
}

// ---------------- init: split codebook into f16 hi + TRUE lo, [q][dc8][code][32] ----------------
__global__ void init_split_kernel(const float* __restrict__ cb, f16* __restrict__ whi,
                                  f16* __restrict__ wlo) {
    int gid = blockIdx.x * 256 + threadIdx.x;   // (q*8+dc)*1024 + k
    int qdc = gid >> 10, k = gid & 1023;
    int q = qdc >> 3, dc = qdc & 7;
    const float* src = cb + ((size_t)(q * 1024 + k)) * 256 + dc * 32;
    size_t wo = (size_t)gid * 32;
#pragma unroll
    for (int jj = 0; jj < 4; ++jj) {
        float4 a = ((const float4*)src)[jj * 2];
        float4 c = ((const float4*)src)[jj * 2 + 1];
        float vals[8] = {a.x, a.y, a.z, a.w, c.x, c.y, c.z, c.w};
        f16x8 hv, lv;
#pragma unroll
        for (int i = 0; i < 8; ++i) {
            f16 h = (f16)vals[i];
            hv[i] = h;
            lv[i] = (f16)(vals[i] - (float)h);    // true lo (f16 subnormals cover it)
        }
        *(f16x8*)&whi[wo + jj * 8] = hv;
        *(f16x8*)&wlo[wo + jj * 8] = lv;
    }
}

// ---------------- main RVQ kernel: 3-product split-f16 MFMA GEMM ----------------
// 8 waves; EACH wave covers all 64 rows (mt=4) x 2 code-cols (nt=2); 4 sweeps of
// 256 codes -> B read EXACTLY ONCE per block per q (L2 demand well under ceiling).
// dc unrolled x2 with alternating B reg sets (no v_mov copy-backs), A row-base
// pointers hoisted (ds-offset imms take +16K/32K/48K B), s_setprio(1) around MFMA
// clusters. Ledger: acc 32 + bval 16 + bidxp 8 + 2 B-sets 32 + A 16 + addr ~14
// = ~118 <= 128 (launch_bounds 512,4).
// R9 = exact revert to R7 (best measured: 945us). R8's bundle (full dc2 unroll +
// cross-barrier B liveness + DPP) re-spilled (FETCH 608->880MB) and lost 8%;
// sweep-boundary latency is already hidden by 4-wave/SIMD TLP.
extern "C" __global__ __launch_bounds__(NTHR, 4)
void rvq_kernel(const float* __restrict__ x, const float* __restrict__ cb,
                const float* __restrict__ csq, const f16* __restrict__ whi,
                const f16* __restrict__ wlo, float* __restrict__ out) {
    extern __shared__ char smem[];
    f16* rs = (f16*)smem;                          // [64][512] halves, granule-swizzled
    float* redv = (float*)(smem + RED_OFF);
    int* redi = (int*)(smem + REDI_OFF);
    float* wsum = (float*)(smem + WSUM_OFF);

    const int tid = threadIdx.x;
    const int w = tid >> 6;
    const int l = tid & 63;
    const int l15 = l & 15;
    const int q4 = l >> 4;

    const int b = blockIdx.x >> 7;
    const int t0 = (blockIdx.x & 127) * TT;
    const float* xb = x + (size_t)b * D_ * T_;

    // residual init: rs[t][d] split of x[b][d][t0+t] (coalesced over t); swizzled store
    for (int d = tid >> 6; d < D_; d += 8) {
        float v = xb[(size_t)d * T_ + t0 + l];
        f16 h = (f16)v;
        const int sw = l & 7;
        rs[l * 512 + (((d >> 3) ^ sw) << 3) + (d & 7)] = h;
        rs[l * 512 + ((((d >> 3) + 32) ^ sw) << 3) + (d & 7)] = (f16)(v - (float)h);
    }

    float ssq = 0.0f;

    // A row-base: invariant across q/sweeps/dc (row = mt*16 + l15)
    const f16* a_base = rs + l15 * 512;
    const int swA = l15 & 7;                       // == row&7 for all A rows of this lane

    for (int q = 0; q < NQ; ++q) {
        const float* cbq = cb + (size_t)q * KB * D_;
        const char* wq = (const char*)(whi + (size_t)q * 8 * KB * 32);
        const char* lq = (const char*)(wlo + (size_t)q * 8 * KB * 32);

        __syncthreads();   // rs ready (init or prev-q update); redv/redi free for this q

        // cross-sweep running best (slot e = mt*4+rg row ownership; codes ascend
        // across sweeps and nt -> strict < keeps first min). bidx packed 2x16b.
        float bval[16];
        unsigned bidxp[8];
#pragma unroll
        for (int e = 0; e < 16; ++e) bval[e] = INFINITY;
#pragma unroll
        for (int p = 0; p < 8; ++p) bidxp[p] = 0;

#pragma unroll 1
        for (int s = 0; s < 4; ++s) {              // 4 sweeps of 256 codes; 32/wave (nt=2)
            const int code0 = s * 256 + w * 32 + l15;
            const int vb0 = (code0 << 6) + q4 * 16;    // byte off into [code][32] tile

            f32x4 ah[4][2];                        // 32 acc VGPRs
#pragma unroll
            for (int mt = 0; mt < 4; ++mt)
#pragma unroll
                for (int nt = 0; nt < 2; ++nt) ah[mt][nt] = (f32x4)0.0f;

            f16x8 sa0h, sa0l, sa1h, sa1l;          // B set A
            f16x8 sb0h, sb0l, sb1h, sb1l;          // B set B

#define LOADSET(p0h, p0l, p1h, p1l, dcv) { \
            const char* wd_ = wq + (dcv) * 65536; \
            const char* ld_ = lq + (dcv) * 65536; \
            p0h = *(const f16x8*)(wd_ + vb0); \
            p0l = *(const f16x8*)(ld_ + vb0); \
            p1h = *(const f16x8*)(wd_ + vb0 + 1024); \
            p1l = *(const f16x8*)(ld_ + vb0 + 1024); }

#define STEP(dcv, c0h, c0l, c1h, c1l) { \
            const int ga_ = (dcv) * 4 + q4; \
            const int o1_ = (ga_ ^ swA) << 3; \
            const int o2_ = ((ga_ + 32) ^ swA) << 3; \
            f16x8 afa1 = *(const f16x8*)&a_base[o1_]; \
            f16x8 afa2 = *(const f16x8*)&a_base[o2_]; \
            f16x8 afb1 = *(const f16x8*)&a_base[8192 + o1_]; \
            f16x8 afb2 = *(const f16x8*)&a_base[8192 + o2_]; \
            __builtin_amdgcn_s_setprio(1); \
            ah[0][0] = MFMA16(afa1, c0h, ah[0][0]); \
            ah[0][0] = MFMA16(afa2, c0h, ah[0][0]); \
            ah[0][0] = MFMA16(afa1, c0l, ah[0][0]); \
            ah[0][1] = MFMA16(afa1, c1h, ah[0][1]); \
            ah[0][1] = MFMA16(afa2, c1h, ah[0][1]); \
            ah[0][1] = MFMA16(afa1, c1l, ah[0][1]); \
            __builtin_amdgcn_sched_barrier(0); \
            afa1 = *(const f16x8*)&a_base[16384 + o1_]; \
            afa2 = *(const f16x8*)&a_base[16384 + o2_]; \
            ah[1][0] = MFMA16(afb1, c0h, ah[1][0]); \
            ah[1][0] = MFMA16(afb2, c0h, ah[1][0]); \
            ah[1][0] = MFMA16(afb1, c0l, ah[1][0]); \
            ah[1][1] = MFMA16(afb1, c1h, ah[1][1]); \
            ah[1][1] = MFMA16(afb2, c1h, ah[1][1]); \
            ah[1][1] = MFMA16(afb1, c1l, ah[1][1]); \
            __builtin_amdgcn_sched_barrier(0); \
            afb1 = *(const f16x8*)&a_base[24576 + o1_]; \
            afb2 = *(const f16x8*)&a_base[24576 + o2_]; \
            ah[2][0] = MFMA16(afa1, c0h, ah[2][0]); \
            ah[2][0] = MFMA16(afa2, c0h, ah[2][0]); \
            ah[2][0] = MFMA16(afa1, c0l, ah[2][0]); \
            ah[2][1] = MFMA16(afa1, c1h, ah[2][1]); \
            ah[2][1] = MFMA16(afa2, c1h, ah[2][1]); \
            ah[2][1] = MFMA16(afa1, c1l, ah[2][1]); \
            __builtin_amdgcn_sched_barrier(0); \
            ah[3][0] = MFMA16(afb1, c0h, ah[3][0]); \
            ah[3][0] = MFMA16(afb2, c0h, ah[3][0]); \
            ah[3][0] = MFMA16(afb1, c0l, ah[3][0]); \
            ah[3][1] = MFMA16(afb1, c1h, ah[3][1]); \
            ah[3][1] = MFMA16(afb2, c1h, ah[3][1]); \
            ah[3][1] = MFMA16(afb1, c1l, ah[3][1]); \
            __builtin_amdgcn_s_setprio(0); \
            __builtin_amdgcn_sched_barrier(0); }

            LOADSET(sa0h, sa0l, sa1h, sa1l, 0)
            LOADSET(sb0h, sb0l, sb1h, sb1l, 1)
#pragma unroll 1
            for (int dc2 = 0; dc2 < 6; dc2 += 2) {
                STEP(dc2, sa0h, sa0l, sa1h, sa1l)
                LOADSET(sa0h, sa0l, sa1h, sa1l, dc2 + 2)
                STEP(dc2 + 1, sb0h, sb0l, sb1h, sb1l)
                LOADSET(sb0h, sb0l, sb1h, sb1l, dc2 + 3)
            }
            STEP(6, sa0h, sa0l, sa1h, sa1l)
            STEP(7, sb0h, sb0l, sb1h, sb1l)
#undef LOADSET
#undef STEP

            // fold sweep into cross-sweep per-lane best (codes ascending -> strict <)
            const float cq0 = csq[q * KB + code0];
            const float cq1 = csq[q * KB + code0 + 16];
#pragma unroll
            for (int nt = 0; nt < 2; ++nt) {
                const int code = code0 + nt * 16;
                const float cq = nt ? cq1 : cq0;
#pragma unroll
                for (int mt = 0; mt < 4; ++mt)
#pragma unroll
                    for (int rg = 0; rg < 4; ++rg) {
                        const int e = mt * 4 + rg;
                        const float dist = fmaf(-2.0f, ah[mt][nt][rg], cq);
                        if (dist < bval[e]) {
                            bval[e] = dist;
                            const int sh = (e & 1) * 16;
                            bidxp[e >> 1] = (bidxp[e >> 1] & ~(0xFFFFu << sh)) |
                                            ((unsigned)code << sh);
                        }
                    }
            }
        }
        // once per q: butterfly across the 16 lanes (codes) sharing each row
#pragma unroll
        for (int m = 1; m < 16; m <<= 1) {
#pragma unroll
            for (int p = 0; p < 8; ++p) {
                const unsigned op = __shfl_xor((int)bidxp[p], m);
#pragma unroll
                for (int h = 0; h < 2; ++h) {
                    const int e = p * 2 + h;
                    const float ov = __shfl_xor(bval[e], m);
                    const int sh = h * 16;
                    const unsigned oc = (op >> sh) & 0xFFFFu;
                    const unsigned mc = (bidxp[p] >> sh) & 0xFFFFu;
                    if (ov < bval[e] || (ov == bval[e] && oc < mc)) {
                        bval[e] = ov;
                        bidxp[p] = (bidxp[p] & ~(0xFFFFu << sh)) | (oc << sh);
                    }
                }
            }
        }
        if (l15 == 0) {
#pragma unroll
            for (int mt = 0; mt < 4; ++mt)
#pragma unroll
                for (int rg = 0; rg < 4; ++rg) {
                    const int e = mt * 4 + rg;
                    const int t = mt * 16 + q4 * 4 + rg;   // C-layout row ownership
                    redv[w * 64 + t] = bval[e];
                    redi[w * 64 + t] = (int)((bidxp[e >> 1] >> ((e & 1) * 16)) & 0xFFFFu);
                }
        }
        __syncthreads();   // all waves' redv/redi final; all GEMM rs reads done
        // merged final-reduce + residual update: thread -> (row t, 32-dim chunk ch)
        {
            const int t = tid & 63, ch = tid >> 6;
            float bv = redv[t];
            int bi = redi[t];
#pragma unroll
            for (int w2 = 1; w2 < 8; ++w2) {
                const float v = redv[w2 * 64 + t];
                const int ii = redi[w2 * 64 + t];
                if (v < bv || (v == bv && ii < bi)) { bv = v; bi = ii; }
            }
            if (ch == 0) out[OUT_CODES + ((size_t)q * B_ + b) * T_ + t0 + t] = (float)bi;
            // residual update: fp32 = hi + lo, subtract cb row, re-split; ssq
            const float* crow = cbq + (size_t)bi * D_ + ch * 32;
            f16* rowp = rs + t * 512;
            const int sw = t & 7;
#pragma unroll
            for (int jj = 0; jj < 4; ++jj) {
                const int g = ch * 4 + jj;
                const int g1 = (g ^ sw) << 3;
                const int g2 = ((g + 32) ^ sw) << 3;
                f16x8 hv = *(const f16x8*)&rowp[g1];
                f16x8 lv = *(const f16x8*)&rowp[g2];
                const float4 c0 = ((const float4*)crow)[jj * 2];
                const float4 c1 = ((const float4*)crow)[jj * 2 + 1];
                const float cc[8] = {c0.x, c0.y, c0.z, c0.w, c1.x, c1.y, c1.z, c1.w};
                f16x8 nh, nl;
#pragma unroll
                for (int i = 0; i < 8; ++i) {
                    const float r = (float)hv[i] + (float)lv[i];
                    const float nv = r - cc[i];
                    ssq = fmaf(nv, nv, ssq);
                    const f16 h = (f16)nv;
                    nh[i] = h;
                    nl[i] = (f16)(nv - (float)h);
                }
                *(f16x8*)&rowp[g1] = nh;
                *(f16x8*)&rowp[g2] = nl;
            }
        }
        // next q's top __syncthreads orders rs writes before A-frag reads
    }
    __syncthreads();
    // quantized = x - r_final, [B][D][T], coalesced over t
    {
        float* outq = out + (size_t)b * D_ * T_;
        for (int d = tid >> 6; d < D_; d += 8) {
            const int sw = l & 7;
            const float h1 = (float)rs[l * 512 + (((d >> 3) ^ sw) << 3) + (d & 7)];
            const float h2 = (float)rs[l * 512 + ((((d >> 3) + 32) ^ sw) << 3) + (d & 7)];
            const size_t gi = (size_t)d * T_ + t0 + l;
            outq[gi] = xb[gi] - (h1 + h2);
        }
    }
    // commit loss: wave reduce -> block reduce -> one atomic
#pragma unroll
    for (int off = 32; off; off >>= 1) ssq += __shfl_down(ssq, off);
    if (l == 0) wsum[w] = ssq;
    __syncthreads();
    if (tid == 0) {
        float tot = 0.0f;
#pragma unroll
        for (int i = 0; i < 8; ++i) tot += wsum[i];
        const float scale = 0.25f / ((float)NQ * (float)B_ * (float)D_ * (float)T_);
        atomicAdd(out + OUT_LOSS, tot * scale);
    }
}

extern "C" void kernel_launch(void* const* d_in, const int* in_sizes, int n_in,
                              void* d_out, int out_size, void* d_ws, size_t ws_size,
                              hipStream_t stream) {
    const float* x = (const float*)d_in[0];
    const int* sr = (const int*)d_in[1];
    const float* cb = (const float*)d_in[2];
    float* out = (float*)d_out;
    float* csq = (float*)d_ws;
    f16* whi = (f16*)((char*)d_ws + WS_HI);
    f16* wlo = (f16*)((char*)d_ws + WS_LO);

    hipFuncSetAttribute((const void*)rvq_kernel, hipFuncAttributeMaxDynamicSharedMemorySize,
                        LDS_TOTAL);

    init_cbsq_kernel<<<2048, 256, 0, stream>>>(cb, sr, csq, out);
    init_split_kernel<<<256, 256, 0, stream>>>(cb, whi, wlo);
    rvq_kernel<<<B_ * (T_ / TT), NTHR, LDS_TOTAL, stream>>>(x, cb, csq, whi, wlo, out);
}